// Round 1
// baseline (259.758 us; speedup 1.0000x reference)
//
#include <hip/hip_runtime.h>

// CIN cross-network, fused MFMA implementation (f16 inputs, fp32 accum).
// Round 4: round-3 register-A structure +
//  (a) 1-wave blocks (64 thr, 4 private batches, 13312B LDS -> 12 blocks/CU,
//      fine-grained scheduling, no ramp/drain cliff of 4-wave blocks)
//  (b) x0 scalars read via half8 chunk loads (ds_read_b128 once per 8 m's
//      per batch) instead of 384 8-way-conflicting ds_read_u16 per wave.
//
// All LDS is wave-private => NO barriers anywhere.

typedef _Float16 half8 __attribute__((ext_vector_type(8)));
typedef _Float16 half2v __attribute__((ext_vector_type(2)));
typedef float f32x4 __attribute__((ext_vector_type(4)));

#define OUT_STRIDE 192
#define X0R 32    // x0 row stride (f16): 64B rows (16B-aligned)
#define X0B 512   // x0 batch stride
#define XKR 72    // xk row stride: 64 + 8 pad (16B-aligned)
#define XKB 1152  // xk batch stride

// ---------------------------------------------------------------------------
// Fused weight repack (verified 16x16 mapping, all 3 layers):
// dst[base + ((t*NKB + kb)*64 + lane)*8 + j] =
//     (f16) W[k -> (m,h)][n = t*16 + (lane&15)],  k = kb*32 + (lane>>4)*8 + j
__global__ void prep_w_all(const float* __restrict__ W0,
                           const float* __restrict__ W1,
                           const float* __restrict__ W2,
                           _Float16* __restrict__ dst) {
  int e = blockIdx.x * 256 + threadIdx.x;   // e < 327680
  const float* W;
  int logH, nkbLog, le;
  if (e < 65536)       { W = W0; logH = 5; nkbLog = 5; le = e; }
  else if (e < 196608) { W = W1; logH = 6; nkbLog = 6; le = e - 65536; }
  else                 { W = W2; logH = 6; nkbLog = 6; le = e - 196608; }
  int j    = le & 7;
  int lane = (le >> 3) & 63;
  int rr   = lane & 15, qq = lane >> 4;
  int rest = le >> 9;
  int kb   = rest & ((1 << nkbLog) - 1);
  int t    = rest >> nkbLog;
  int k    = kb * 32 + qq * 8 + j;
  int H    = 1 << logH;
  int m    = k >> logH, h = k & (H - 1);
  int n    = t * 16 + rr;
  dst[e] = (_Float16)W[(m * H + h) * 64 + n];
}

// ---------------------------------------------------------------------------
// One layer for one wave's 4 private batches.
// NHI: number of 32-wide h-blocks (1 for H=32, 2 for H=64). K-blocks: NKB=32*NHI.
// av[b][hi] = xk-vector (8 f16 at h = hi*32 + q*8 + j) held in registers.
template<int NHI, bool LAST>
__device__ __forceinline__ void run_layer(
    const _Float16* __restrict__ Wp, const half8 (&av)[4][NHI],
    const _Float16* x0s, _Float16* xkw, float* __restrict__ out,
    long gb0, int loff, int lane, int r, int q)
{
  const int NKB = 32 * NHI;
  f32x4 acc[4][4];
#pragma unroll
  for (int b = 0; b < 4; ++b)
#pragma unroll
    for (int t = 0; t < 4; ++t) acc[b][t] = (f32x4){0.f, 0.f, 0.f, 0.f};

  const _Float16* Wl = Wp + lane * 8;

#pragma unroll 2
  for (int mo = 0; mo < 4; ++mo) {
    // x0 row chunk per batch: 8 m-scalars in one ds_read_b128 (replaces
    // 8 scalar ds_read_u16 with 8-way bank conflicts).
    half8 xc[4];
#pragma unroll
    for (int b = 0; b < 4; ++b)
      xc[b] = *(const half8*)(x0s + b * X0B + r * X0R + mo * 8);

#pragma unroll
    for (int m8 = 0; m8 < 8; ++m8) {
      const int m = mo * 8 + m8;
      // x0 scalar per batch for this m (broadcast to half2 for v_pk_mul_f16).
      half2v xs2[4];
#pragma unroll
      for (int b = 0; b < 4; ++b) {
        _Float16 x = xc[b][m8];
        xs2[b] = (half2v){x, x};
      }
#pragma unroll
      for (int hi = 0; hi < NHI; ++hi) {
        const int kb = m * NHI + hi;
        half8 Bf[4];
#pragma unroll
        for (int t = 0; t < 4; ++t)
          Bf[t] = *(const half8*)(Wl + (size_t)(t * NKB + kb) * 512);
#pragma unroll
        for (int b = 0; b < 4; ++b) {
          half8 af;
          half2v* ap = (half2v*)&af;
          const half2v* vp = (const half2v*)&av[b][hi];
#pragma unroll
          for (int j2 = 0; j2 < 4; ++j2) ap[j2] = vp[j2] * xs2[b];
#pragma unroll
          for (int t = 0; t < 4; ++t)
            acc[b][t] = __builtin_amdgcn_mfma_f32_16x16x32_f16(
                af, Bf[t], acc[b][t], 0, 0, 0);
        }
      }
    }
  }

  // Epilogue (verified). C/D layout: col n = r, row d = q*4 + reg.
#pragma unroll
  for (int b = 0; b < 4; ++b) {
#pragma unroll
    for (int t = 0; t < 4; ++t) {
      float s = 0.f;
#pragma unroll
      for (int rr = 0; rr < 4; ++rr) {
        float v = acc[b][t][rr];
        v = v > 0.f ? v : 0.f;
        s += v;
        if (!LAST)
          xkw[b * XKB + (q * 4 + rr) * XKR + t * 16 + r] = (_Float16)v;
      }
      s += __shfl_xor(s, 16);
      s += __shfl_xor(s, 32);
      if (q == 0)
        out[(gb0 + b) * OUT_STRIDE + loff + t * 16 + r] = s;
    }
  }
}

__global__ __launch_bounds__(64, 3) void cin_main(
    const float* __restrict__ emb, const _Float16* __restrict__ Wall,
    float* __restrict__ out)
{
  // Per-block (1 wave): x0 4 batches * 512 f16 = 4096 B
  //                     xk 4 batches * 1152 f16 = 9216 B
  // total 13312 B -> 12 blocks/CU (12 waves/CU, 3/SIMD).
  __shared__ __align__(16) _Float16 lds[4 * X0B + 4 * XKB];
  const int lane = threadIdx.x & 63;
  const int r = lane & 15, q = lane >> 4;
  const long gb0 = (long)blockIdx.x * 4;

  _Float16* x0w = lds;
  _Float16* xkw = &lds[4 * X0B];

  // Stage this wave's 4 batches: read (m,d) fp32, write transposed (d,m) f16.
#pragma unroll
  for (int bb = 0; bb < 4; ++bb) {
    const float* src = emb + (gb0 + bb) * 512;
    _Float16* dstb = x0w + bb * X0B;
#pragma unroll
    for (int i = 0; i < 2; ++i) {
      int f = i * 256 + lane * 4;         // flat = m*16 + d, d aligned to 4
      float4 v = *(const float4*)(src + f);
      int m = f >> 4, d = f & 15;
      dstb[(d + 0) * X0R + m] = (_Float16)v.x;
      dstb[(d + 1) * X0R + m] = (_Float16)v.y;
      dstb[(d + 2) * X0R + m] = (_Float16)v.z;
      dstb[(d + 3) * X0R + m] = (_Float16)v.w;
    }
  }
  // All LDS regions are wave-private: program order + waitcnt suffice.

  // Layer 1: A-vectors from x0 (h = q*8+j, single h-block).
  half8 av1[4][1];
#pragma unroll
  for (int b = 0; b < 4; ++b)
    av1[b][0] = *(const half8*)(x0w + b * X0B + r * X0R + q * 8);
  run_layer<1, false>(Wall, av1, x0w, xkw, out, gb0, 0, lane, r, q);

  // Layer 2: A-vectors from xk (h = hi*32 + q*8 + j).
  half8 av2[4][2];
#pragma unroll
  for (int b = 0; b < 4; ++b)
#pragma unroll
    for (int hi = 0; hi < 2; ++hi)
      av2[b][hi] = *(const half8*)(xkw + b * XKB + r * XKR + hi * 32 + q * 8);
  run_layer<2, false>(Wall + 65536, av2, x0w, xkw, out, gb0, 64, lane, r, q);

  // Layer 3: reload A-vectors (layer 2 rewrote xk).
#pragma unroll
  for (int b = 0; b < 4; ++b)
#pragma unroll
    for (int hi = 0; hi < 2; ++hi)
      av2[b][hi] = *(const half8*)(xkw + b * XKB + r * XKR + hi * 32 + q * 8);
  run_layer<2, true>(Wall + 196608, av2, x0w, xkw, out, gb0, 128, lane, r, q);
}

extern "C" void kernel_launch(void* const* d_in, const int* in_sizes, int n_in,
                              void* d_out, int out_size, void* d_ws, size_t ws_size,
                              hipStream_t stream) {
  const float* emb = (const float*)d_in[0];
  const float* W0  = (const float*)d_in[1];
  const float* W1  = (const float*)d_in[2];
  const float* W2  = (const float*)d_in[3];
  float* out = (float*)d_out;
  _Float16* ws = (_Float16*)d_ws;   // needs 327680 f16 = 640 KB

  // Single fused weight repack (327680 elements).
  prep_w_all<<<1280, 256, 0, stream>>>(W0, W1, W2, ws);

  // 16384 batches / 4 per block = 4096 blocks of 64 threads (1 wave x 4 b).
  cin_main<<<4096, 64, 0, stream>>>(emb, ws, out);
}

// Round 2
// 207.098 us; speedup vs baseline: 1.2543x; 1.2543x over previous
//
#include <hip/hip_runtime.h>

// CIN cross-network, fused MFMA implementation (f16 inputs, fp32 accum).
// Round 5: EXACT round-3 structure (256-thr blocks, 4 waves x 4 private
// batches, unroll-2 m-loop, no barriers) with ONE change: x0 is stored
// M-MAJOR in LDS (x0t[m*16+d]).
//  - per-m scalar read x0t[m*16 + r]: 16 r-lanes hit 8 consecutive dwords
//    (8 banks, pairs/q-replicas broadcast) -> conflict-free, vs 8-way
//    conflict of the old d-major layout (was 14% of CU cycles).
//  - staging is now a straight copy (emb is (m,d) row-major already):
//    aligned ds_write_b64, no transpose scatter.
//  - only layer-1 av setup changes: 8 strided u16 reads per batch (one-time).
// Round-4 lesson: keep the m-loop body at 2 m's; 16-m unrolled bodies
// caused scratch traffic (86 MB phantom writes) and latency-bound collapse.

typedef _Float16 half8 __attribute__((ext_vector_type(8)));
typedef _Float16 half4 __attribute__((ext_vector_type(4)));
typedef _Float16 half2v __attribute__((ext_vector_type(2)));
typedef float f32x4 __attribute__((ext_vector_type(4)));

#define OUT_STRIDE 192
#define X0B 512   // x0 batch stride (m-major: m*16 + d, 32x16 halfs)
#define XKR 72    // xk row stride: 64 + 8 pad (16B-aligned)
#define XKB 1152  // xk batch stride

// ---------------------------------------------------------------------------
// Fused weight repack (verified 16x16 mapping, all 3 layers):
// dst[base + ((t*NKB + kb)*64 + lane)*8 + j] =
//     (f16) W[k -> (m,h)][n = t*16 + (lane&15)],  k = kb*32 + (lane>>4)*8 + j
__global__ void prep_w_all(const float* __restrict__ W0,
                           const float* __restrict__ W1,
                           const float* __restrict__ W2,
                           _Float16* __restrict__ dst) {
  int e = blockIdx.x * 256 + threadIdx.x;   // e < 327680
  const float* W;
  int logH, nkbLog, le;
  if (e < 65536)       { W = W0; logH = 5; nkbLog = 5; le = e; }
  else if (e < 196608) { W = W1; logH = 6; nkbLog = 6; le = e - 65536; }
  else                 { W = W2; logH = 6; nkbLog = 6; le = e - 196608; }
  int j    = le & 7;
  int lane = (le >> 3) & 63;
  int rr   = lane & 15, qq = lane >> 4;
  int rest = le >> 9;
  int kb   = rest & ((1 << nkbLog) - 1);
  int t    = rest >> nkbLog;
  int k    = kb * 32 + qq * 8 + j;
  int H    = 1 << logH;
  int m    = k >> logH, h = k & (H - 1);
  int n    = t * 16 + rr;
  dst[e] = (_Float16)W[(m * H + h) * 64 + n];
}

// ---------------------------------------------------------------------------
// One layer for one wave's 4 private batches.
// NHI: number of 32-wide h-blocks (1 for H=32, 2 for H=64). K-blocks: NKB=32*NHI.
// av[b][hi] = xk-vector (8 f16 at h = hi*32 + q*8 + j) held in registers.
// x0s is M-MAJOR: x0s[b*X0B + m*16 + d].
template<int NHI, bool LAST>
__device__ __forceinline__ void run_layer(
    const _Float16* __restrict__ Wp, const half8 (&av)[4][NHI],
    const _Float16* x0s, _Float16* xkw, float* __restrict__ out,
    long gb0, int loff, int lane, int r, int q)
{
  const int NKB = 32 * NHI;
  f32x4 acc[4][4];
#pragma unroll
  for (int b = 0; b < 4; ++b)
#pragma unroll
    for (int t = 0; t < 4; ++t) acc[b][t] = (f32x4){0.f, 0.f, 0.f, 0.f};

  const _Float16* Wl = Wp + lane * 8;

#pragma unroll 2
  for (int m = 0; m < 32; ++m) {
    // x0 scalar per batch for this m: m-major read -> conflict-free
    // (16 r-lanes span 8 consecutive dwords; pairs/q-replicas broadcast).
    half2v xs2[4];
#pragma unroll
    for (int b = 0; b < 4; ++b) {
      _Float16 x = x0s[b * X0B + m * 16 + r];
      xs2[b] = (half2v){x, x};
    }
#pragma unroll
    for (int hi = 0; hi < NHI; ++hi) {
      const int kb = m * NHI + hi;
      half8 Bf[4];
#pragma unroll
      for (int t = 0; t < 4; ++t)
        Bf[t] = *(const half8*)(Wl + (size_t)(t * NKB + kb) * 512);
#pragma unroll
      for (int b = 0; b < 4; ++b) {
        half8 af;
        half2v* ap = (half2v*)&af;
        const half2v* vp = (const half2v*)&av[b][hi];
#pragma unroll
        for (int j2 = 0; j2 < 4; ++j2) ap[j2] = vp[j2] * xs2[b];
#pragma unroll
        for (int t = 0; t < 4; ++t)
          acc[b][t] = __builtin_amdgcn_mfma_f32_16x16x32_f16(
              af, Bf[t], acc[b][t], 0, 0, 0);
      }
    }
  }

  // Epilogue (verified). C/D layout: col n = r, row d = q*4 + reg.
#pragma unroll
  for (int b = 0; b < 4; ++b) {
#pragma unroll
    for (int t = 0; t < 4; ++t) {
      float s = 0.f;
#pragma unroll
      for (int rr = 0; rr < 4; ++rr) {
        float v = acc[b][t][rr];
        v = v > 0.f ? v : 0.f;
        s += v;
        if (!LAST)
          xkw[b * XKB + (q * 4 + rr) * XKR + t * 16 + r] = (_Float16)v;
      }
      s += __shfl_xor(s, 16);
      s += __shfl_xor(s, 32);
      if (q == 0)
        out[(gb0 + b) * OUT_STRIDE + loff + t * 16 + r] = s;
    }
  }
}

__global__ __launch_bounds__(256, 3) void cin_main(
    const float* __restrict__ emb, const _Float16* __restrict__ Wall,
    float* __restrict__ out)
{
  // x0: 16 batches * 512 f16 (m-major) = 16384 B
  // xk: 16 batches * 1152 f16 (16 d rows of stride 72) = 36864 B
  // total 53248 B -> 3 blocks/CU.
  __shared__ __align__(16) _Float16 lds[16 * X0B + 16 * XKB];
  const int lane = threadIdx.x & 63;
  const int wv = threadIdx.x >> 6;
  const int r = lane & 15, q = lane >> 4;
  const long gb0 = (long)blockIdx.x * 16 + wv * 4;

  _Float16* x0w = &lds[wv * 4 * X0B];
  _Float16* xkw = &lds[16 * X0B + wv * 4 * XKB];

  // Stage this wave's 4 batches: emb is (m,d) row-major = the LDS layout.
  // Straight f32->f16 copy, aligned 8B LDS writes, no transpose.
#pragma unroll
  for (int bb = 0; bb < 4; ++bb) {
    const float* src = emb + (gb0 + bb) * 512;
    _Float16* dstb = x0w + bb * X0B;
#pragma unroll
    for (int i = 0; i < 2; ++i) {
      int f = i * 256 + lane * 4;
      float4 v = *(const float4*)(src + f);
      half4 h = {(_Float16)v.x, (_Float16)v.y, (_Float16)v.z, (_Float16)v.w};
      *(half4*)(dstb + f) = h;
    }
  }
  // All LDS regions are wave-private: program order + waitcnt suffice.

  // Layer 1: A-vectors from x0 (xk==x0, indexed by h along the m axis).
  // m-major layout -> 8 strided u16 reads per batch (one-time, outside loop).
  half8 av1[4][1];
#pragma unroll
  for (int b = 0; b < 4; ++b) {
#pragma unroll
    for (int j = 0; j < 8; ++j)
      av1[b][0][j] = x0w[b * X0B + (q * 8 + j) * 16 + r];
  }
  run_layer<1, false>(Wall, av1, x0w, xkw, out, gb0, 0, lane, r, q);

  // Layer 2: A-vectors from xk (h = hi*32 + q*8 + j), d-major xk layout.
  half8 av2[4][2];
#pragma unroll
  for (int b = 0; b < 4; ++b)
#pragma unroll
    for (int hi = 0; hi < 2; ++hi)
      av2[b][hi] = *(const half8*)(xkw + b * XKB + r * XKR + hi * 32 + q * 8);
  run_layer<2, false>(Wall + 65536, av2, x0w, xkw, out, gb0, 64, lane, r, q);

  // Layer 3: reload A-vectors (layer 2 rewrote xk).
#pragma unroll
  for (int b = 0; b < 4; ++b)
#pragma unroll
    for (int hi = 0; hi < 2; ++hi)
      av2[b][hi] = *(const half8*)(xkw + b * XKB + r * XKR + hi * 32 + q * 8);
  run_layer<2, true>(Wall + 196608, av2, x0w, xkw, out, gb0, 128, lane, r, q);
}

extern "C" void kernel_launch(void* const* d_in, const int* in_sizes, int n_in,
                              void* d_out, int out_size, void* d_ws, size_t ws_size,
                              hipStream_t stream) {
  const float* emb = (const float*)d_in[0];
  const float* W0  = (const float*)d_in[1];
  const float* W1  = (const float*)d_in[2];
  const float* W2  = (const float*)d_in[3];
  float* out = (float*)d_out;
  _Float16* ws = (_Float16*)d_ws;   // needs 327680 f16 = 640 KB

  // Single fused weight repack (327680 elements).
  prep_w_all<<<1280, 256, 0, stream>>>(W0, W1, W2, ws);

  // 16384 batches / 16 per block = 1024 blocks of 256 threads (4 waves x 4 b).
  cin_main<<<1024, 256, 0, stream>>>(emb, ws, out);
}